// Round 5
// baseline (47.935 us; speedup 1.0000x reference)
//
#include <hip/hip_runtime.h>

// Shapes fixed by setup_inputs(): b=8, t=128, k=128, h=4, m=t-1=127.
#define KD 128
#define NH 4
#define MM 127
#define NO 516

// workspace layout (float offsets)
#define OFF_W1S 0                      // [4][128]   score rows of W1
#define OFF_WC  512                    // [4][256][128]  Wct[h][c][dd]  (c-major)
#define OFF_C   (512 + 131072)         // [1024][512]  weighted kv sums per (bt, h*128+d)

// ---------------------------------------------------------------------------
// Kernel 1: W1[o][k] = sum_j Wv[o][j]*Wk[j][k],  W2[o][k] = sum_j Wv[o][128+j]*Wq[j][k]
// Score rows (o%129==0) -> OFF_W1S. Value rows -> Wct[h][c][dd] (c-major).
// (q/W2/bias terms are constant in m -> cancel in softmax -> dropped from scores.)
// ---------------------------------------------------------------------------
__global__ void precompute_w(const float* __restrict__ Wk,
                             const float* __restrict__ Wq,
                             const float* __restrict__ Wv,
                             float* __restrict__ ws) {
    int o = blockIdx.x;        // 0..515
    int k = threadIdx.x;       // 0..127
    const float* wvrow = Wv + o * 256;
    float acc1 = 0.f, acc2 = 0.f;
    #pragma unroll 8
    for (int j = 0; j < 128; ++j) {
        acc1 += wvrow[j]       * Wk[j * 128 + k];
        acc2 += wvrow[128 + j] * Wq[j * 128 + k];
    }
    int h = o / 129;
    int r = o - h * 129;
    if (r == 0) {
        ws[OFF_W1S + h * 128 + k] = acc1;
    } else {
        int dd = r - 1;
        ws[OFF_WC + (size_t)(h * 256 + k) * 128 + dd]       = acc1;
        ws[OFF_WC + (size_t)(h * 256 + 128 + k) * 128 + dd] = acc2;
    }
}

// ---------------------------------------------------------------------------
// Kernel 2: per (b,t): fused stage+scores -> softmax -> csum from LDS.
// No register-resident kv tile (the round-2..4 version spilled it to scratch:
// VGPR_Count=60 < the 96+ needed -> 42us. Here kv lives in LDS.)
// ---------------------------------------------------------------------------
__global__ __launch_bounds__(256, 2)
void attn_csum(const float* __restrict__ kv_x, float* __restrict__ ws) {
    __shared__ float skv[MM * KD];     // kv tile        (65024 B)
    __shared__ float ssc[512];         // scores [m][h]  (2 KB)
    __shared__ float swt[512];         // weights [m][h] (2 KB)
    __shared__ float cpart[2][512];    // m-half partials (4 KB)

    const int bt  = blockIdx.x;
    const int tid = threadIdx.x;
    const int dq  = tid & 31;          // d-quad (d = dq*4+j)
    const int g   = tid >> 5;          // half-wave group 0..7

    // score-projection fragments for my d-quad, all 4 heads (L2-hot, 512B/row)
    float4 w1s[NH];
    #pragma unroll
    for (int h = 0; h < NH; ++h)
        w1s[h] = *(const float4*)(ws + OFF_W1S + h * KD + dq * 4);

    const float4* src = (const float4*)(kv_x + (size_t)bt * MM * KD);
    const int bit4 = (tid >> 4) & 1;
    const int bit3 = (tid >> 3) & 1;
    const int myh  = bit4 * 2 + bit3;

    // ---- fused stage + scores: chunk k covers rows m = g + 8k ----
    #pragma unroll
    for (int k = 0; k < 16; ++k) {
        int idx = tid + k * 256;
        int m   = g + 8 * k;
        bool valid = (m < MM);                 // uniform per half-wave
        float4 v = valid ? src[idx] : make_float4(0.f, 0.f, 0.f, 0.f);
        if (valid) *(float4*)&skv[m * KD + dq * 4] = v;   // b128, conflict-free
        // 4-head partials on this quad
        float p0 = v.x*w1s[0].x + v.y*w1s[0].y + v.z*w1s[0].z + v.w*w1s[0].w;
        float p1 = v.x*w1s[1].x + v.y*w1s[1].y + v.z*w1s[1].z + v.w*w1s[1].w;
        float p2 = v.x*w1s[2].x + v.y*w1s[2].y + v.z*w1s[2].z + v.w*w1s[2].w;
        float p3 = v.x*w1s[3].x + v.y*w1s[3].y + v.z*w1s[3].z + v.w*w1s[3].w;
        // head-splitting butterfly over the 32-lane group
        float x = bit4 ? p0 : p2;
        float y = bit4 ? p1 : p3;
        float a = (bit4 ? p2 : p0) + __shfl_xor(x, 16);
        float b = (bit4 ? p3 : p1) + __shfl_xor(y, 16);
        float z = bit3 ? a : b;
        float vr = (bit3 ? b : a) + __shfl_xor(z, 8);
        vr += __shfl_xor(vr, 4);
        vr += __shfl_xor(vr, 2);
        vr += __shfl_xor(vr, 1);
        if ((tid & 7) == 0 && valid) ssc[m * 4 + myh] = vr;
    }
    __syncthreads();

    // ---- softmax over m: one wave per head ----
    {
        int h = tid >> 6, lane = tid & 63;
        float v0 = ssc[lane * 4 + h];
        bool has1 = (lane + 64) < MM;
        float v1 = has1 ? ssc[(lane + 64) * 4 + h] : -1e30f;
        float mx = fmaxf(v0, v1);
        #pragma unroll
        for (int off = 32; off; off >>= 1) mx = fmaxf(mx, __shfl_xor(mx, off));
        float e0 = __expf(v0 - mx);
        float e1 = has1 ? __expf(v1 - mx) : 0.f;
        float s = e0 + e1;
        #pragma unroll
        for (int off = 32; off; off >>= 1) s += __shfl_xor(s, off);
        float inv = 1.f / s;
        swt[lane * 4 + h] = e0 * inv;
        if (has1) swt[(lane + 64) * 4 + h] = e1 * inv;
    }
    __syncthreads();

    // ---- csum: thread = (dq, head, m-half); c[h][d] = sum_m w[m,h]*kv[m][d]
    {
        const int ch = (tid >> 5) & 3;     // head
        const int mh = tid >> 7;           // m-half (wave-uniform)
        const int m0 = mh ? 64 : 0;
        const int m1 = mh ? MM : 64;
        float4 fa = make_float4(0.f, 0.f, 0.f, 0.f);
        #pragma unroll 8
        for (int m = m0; m < m1; ++m) {
            float w = swt[m * 4 + ch];                         // broadcast
            float4 kq = *(const float4*)&skv[m * KD + dq * 4]; // b128
            fa.x += w * kq.x; fa.y += w * kq.y;
            fa.z += w * kq.z; fa.w += w * kq.w;
        }
        *(float4*)&cpart[mh][ch * KD + dq * 4] = fa;
    }
    __syncthreads();

    // ---- reduce 2 halves, coalesced float4 write of c ----
    if (tid < 128) {
        float4 a = *(const float4*)&cpart[0][tid * 4];
        float4 b = *(const float4*)&cpart[1][tid * 4];
        float4 s;
        s.x = a.x + b.x; s.y = a.y + b.y; s.z = a.z + b.z; s.w = a.w + b.w;
        *(float4*)(ws + OFF_C + (size_t)bt * 512 + tid * 4) = s;
    }
}

// ---------------------------------------------------------------------------
// Kernel 3: out[r][h*128+dd] = sum_c A_h[r][c]*Wct[h][c][dd] + bv,  K=256,
// A_h[r] = [ c[r][h][0:128] | q_x[r][0:128] ].
// BM=32 x BN=64, BK=64, 256 WGs, 2x4 register blocking, b64/b128 LDS reads.
// ---------------------------------------------------------------------------
#define BM 32
#define BN 64
#define BK 64
#define AP 34   // sAT row pad (even -> b64-aligned, 2-way max)
#define BP 68   // sB row pad (16B-aligned float4 reads, conflict-free)

__global__ __launch_bounds__(256, 2)
void proj_out(const float* __restrict__ q_x,
              const float* __restrict__ bv,
              const float* __restrict__ ws,
              float* __restrict__ out) {
    __shared__ float sAT[BK][AP];   // A transposed [c][r]
    __shared__ float sB[BK][BP];    // B [c][dd]

    const int r0  = blockIdx.x * BM;
    const int dd0 = blockIdx.y * BN;
    const int h   = blockIdx.z;
    const int tid = threadIdx.x;
    const int tx  = tid & 15;       // 16 col-groups x 4 cols
    const int ty  = tid >> 4;       // 16 row-groups x 2 rows
    const float* cmat = ws + OFF_C;
    const float* Wct  = ws + OFF_WC;

    float acc[2][4];
    #pragma unroll
    for (int i = 0; i < 2; ++i)
        #pragma unroll
        for (int j = 0; j < 4; ++j) acc[i][j] = 0.f;

    for (int ks = 0; ks < 4; ++ks) {
        int kk0 = ks * BK;
        // stage A transposed: 32 rows x 64 c
        const float* Abase; int Astride;
        if (kk0 < 128) { Abase = cmat + h * KD + kk0; Astride = 512; }
        else           { Abase = q_x + (kk0 - 128);   Astride = KD;  }
        #pragma unroll
        for (int i = 0; i < 2; ++i) {
            int idx = tid + i * 256;         // 0..511
            int r = idx >> 4, c4 = idx & 15;
            float4 v = *(const float4*)(Abase + (size_t)(r0 + r) * Astride + c4 * 4);
            sAT[c4 * 4 + 0][r] = v.x;
            sAT[c4 * 4 + 1][r] = v.y;
            sAT[c4 * 4 + 2][r] = v.z;
            sAT[c4 * 4 + 3][r] = v.w;
        }
        // stage B: 64 c-rows x 64 dd, direct coalesced copy
        #pragma unroll
        for (int i = 0; i < 4; ++i) {
            int idx = tid + i * 256;         // 0..1023
            int c = idx >> 4, d4 = idx & 15;
            *(float4*)&sB[c][d4 * 4] =
                *(const float4*)(Wct + (size_t)(h * 256 + kk0 + c) * 128 + dd0 + d4 * 4);
        }
        __syncthreads();
        #pragma unroll 8
        for (int c = 0; c < BK; ++c) {
            float2 a  = *(const float2*)&sAT[c][ty * 2];
            float4 b4 = *(const float4*)&sB[c][tx * 4];
            acc[0][0] += a.x * b4.x; acc[0][1] += a.x * b4.y;
            acc[0][2] += a.x * b4.z; acc[0][3] += a.x * b4.w;
            acc[1][0] += a.y * b4.x; acc[1][1] += a.y * b4.y;
            acc[1][2] += a.y * b4.z; acc[1][3] += a.y * b4.w;
        }
        __syncthreads();
    }
    // epilogue: + bias, coalesced float4 stores
    float bb[4];
    #pragma unroll
    for (int j = 0; j < 4; ++j) bb[j] = bv[h * 129 + 1 + dd0 + tx * 4 + j];
    #pragma unroll
    for (int i = 0; i < 2; ++i) {
        float4 v;
        v.x = acc[i][0] + bb[0];
        v.y = acc[i][1] + bb[1];
        v.z = acc[i][2] + bb[2];
        v.w = acc[i][3] + bb[3];
        *(float4*)(out + (size_t)(r0 + ty * 2 + i) * 512 + h * KD + dd0 + tx * 4) = v;
    }
}

extern "C" void kernel_launch(void* const* d_in, const int* in_sizes, int n_in,
                              void* d_out, int out_size, void* d_ws, size_t ws_size,
                              hipStream_t stream) {
    const float* q_x  = (const float*)d_in[0];
    const float* kv_x = (const float*)d_in[1];
    const float* Wk   = (const float*)d_in[2];
    const float* Wq   = (const float*)d_in[3];
    const float* Wv   = (const float*)d_in[4];
    const float* bv   = (const float*)d_in[5];
    float* out = (float*)d_out;
    float* ws  = (float*)d_ws;

    int bt = in_sizes[0] / KD;   // 1024

    hipLaunchKernelGGL(precompute_w, dim3(NO), dim3(128), 0, stream, Wk, Wq, Wv, ws);
    hipLaunchKernelGGL(attn_csum, dim3(bt), dim3(256), 0, stream, kv_x, ws);
    hipLaunchKernelGGL(proj_out, dim3(bt / BM, KD / BN, NH), dim3(256), 0, stream,
                       q_x, bv, ws, out);
}